// Round 3
// baseline (125.557 us; speedup 1.0000x reference)
//
#include <hip/hip_runtime.h>

// B=20000, C=64, D=27
// out0[b,c,i,j] = sum_k T1[b,c,3i+k] * T2[b,9k+j] / sqrt(3)   (i,j in 0..8, k in 0..2)
// out1[b,c,i,j] = sum_k T1[b,c,9i+k] * T2[b,3k+j] / 3         (i,j in 0..2, k in 0..8)
// out2[b,c]     = dot(T1[b,c,:27], T2[b,:27]) / sqrt(27)

constexpr int D_DIM      = 27;
constexpr int T1_PER_B   = 1728;   // 64*27 floats = 432 float4
constexpr int OUT0_PER_B = 5184;   // 1296 float4
constexpr int OUT1_PER_B = 576;    // 144 float4
constexpr int OUT2_PER_B = 64;

__global__ __launch_bounds__(256, 5) void atc_kernel(
    const float* __restrict__ T1, const float* __restrict__ T2,
    float* __restrict__ out0, float* __restrict__ out1, float* __restrict__ out2,
    int B)
{
    // sT1d[w][j] = T1[b, 3j+w]  — mod-3 float de-interleave.
    // out0 thread t: rows 4t..4t+3 need T1[12t + 3*rr + w] = sT1d[w][4t+rr]
    //   -> one lane-consecutive ds_read_b128 per w (conflict-free).
    // out1 row R: T1[9R+3p+w] = sT1d[w][3R+p]; out2 c: T1[27c+3p+w] = sT1d[w][9c+p]
    //   -> contiguous compile-time-offset runs.
    __shared__ __align__(16) float sT1d[3][576];   //  6912 B
    // sO0 slot (t + 144*m) holds output float4 index (9t + m)  — interleaved so the
    // 9 per-thread f4 writes are lane-consecutive (conflict-free; any LINEAR stride
    // would 8-way alias for lanes 8 apart since stride*8 == 0 mod 8 bank-groups).
    __shared__ __align__(16) float sO0[OUT0_PER_B]; // 20736 B
    __shared__ __align__(16) float sO1[OUT1_PER_B]; //  2304 B
    // total 29952 B -> 5 blocks/CU -> 20 waves/CU

    const int tid = threadIdx.x;
    const float n0 = 0.57735026918962576f;  // 1/sqrt(3)
    const float n1 = 0.33333333333333333f;  // 1/3
    const float n2 = 0.19245008972987526f;  // 1/sqrt(27)

    for (int b = blockIdx.x; b < B; b += gridDim.x) {
        // ---- T2[b]: wave-uniform addresses -> s_load / registers, all uses compile-time indexed
        const float* t2p = T2 + (size_t)b * D_DIM;
        float s2[D_DIM];
        #pragma unroll
        for (int d = 0; d < D_DIM; ++d) s2[d] = t2p[d];

        // ---- stage T1[b]: coalesced float4 global loads, de-interleaved scatter ds_write_b32
        const float4* t1v = reinterpret_cast<const float4*>(T1 + (size_t)b * T1_PER_B);
        {
            // float f = 4g+u: f%3 = (gm3+u)%3, f/3 = g + gd3 + ((gm3+u)>=3)
            float4 v = t1v[tid];
            const int g = tid, gd3 = g / 3, gm3 = g - gd3 * 3;
            #pragma unroll
            for (int u = 0; u < 4; ++u) {
                const int t  = gm3 + u;
                const int ge = (t >= 3) ? 1 : 0;
                sT1d[t - 3 * ge][g + gd3 + ge] = (&v.x)[u];
            }
            if (tid < 176) {
                const int g2 = 256 + tid, gd3b = g2 / 3, gm3b = g2 - gd3b * 3;
                float4 v2 = t1v[g2];
                #pragma unroll
                for (int u = 0; u < 4; ++u) {
                    const int t  = gm3b + u;
                    const int ge = (t >= 3) ? 1 : 0;
                    sT1d[t - 3 * ge][g2 + gd3b + ge] = (&v2.x)[u];
                }
            }
        }
        __syncthreads();

        // ---- out0: threads 0-143, 4 whole rows each (36 outputs = 9 aligned float4)
        if (tid < 144) {
            const float4* A0p = reinterpret_cast<const float4*>(&sT1d[0][0]);
            const float4* A1p = reinterpret_cast<const float4*>(&sT1d[1][0]);
            const float4* A2p = reinterpret_cast<const float4*>(&sT1d[2][0]);
            const float4 A0 = A0p[tid], A1 = A1p[tid], A2 = A2p[tid];
            const float a0[4] = {A0.x * n0, A0.y * n0, A0.z * n0, A0.w * n0};
            const float a1[4] = {A1.x * n0, A1.y * n0, A1.z * n0, A1.w * n0};
            const float a2[4] = {A2.x * n0, A2.y * n0, A2.z * n0, A2.w * n0};
            float4* so0 = reinterpret_cast<float4*>(sO0);
            #pragma unroll
            for (int m = 0; m < 9; ++m) {
                float4 r;
                #pragma unroll
                for (int u = 0; u < 4; ++u) {
                    const int e  = 4 * m + u;     // 0..35, compile-time
                    const int rr = e / 9;         // row within thread
                    const int j  = e - rr * 9;
                    (&r.x)[u] = a0[rr] * s2[j] + a1[rr] * s2[9 + j] + a2[rr] * s2[18 + j];
                }
                so0[tid + 144 * m] = r;           // lane-consecutive -> conflict-free
            }
        }

        // ---- out1: threads 0-191, one (c,i) row each; out2: threads 192-255 (wave 3)
        if (tid < 192) {
            const int R = tid;                     // R = 3c+i
            float av[3][3];
            #pragma unroll
            for (int w = 0; w < 3; ++w)
                #pragma unroll
                for (int p = 0; p < 3; ++p)
                    av[w][p] = sT1d[w][3 * R + p]; // = T1[9R + 3p + w]
            #pragma unroll
            for (int j = 0; j < 3; ++j) {
                float v = 0.f;
                #pragma unroll
                for (int k = 0; k < 9; ++k)        // k = 3p + w
                    v += av[k % 3][k / 3] * s2[3 * k + j];
                sO1[3 * R + j] = v * n1;
            }
        } else {
            const int c = tid - 192;
            float v = 0.f;
            #pragma unroll
            for (int w = 0; w < 3; ++w)
                #pragma unroll
                for (int p = 0; p < 9; ++p)        // d = 3p + w
                    v += sT1d[w][9 * c + p] * s2[3 * p + w];
            out2[(size_t)b * OUT2_PER_B + c] = v * n2;
        }
        __syncthreads();

        // ---- readback: perfectly coalesced float4 global stores
        float4* o0 = reinterpret_cast<float4*>(out0 + (size_t)b * OUT0_PER_B);
        const float4* s0v = reinterpret_cast<const float4*>(sO0);
        #pragma unroll
        for (int q = 0; q < 5; ++q) {
            const int F = q * 256 + tid;
            const int t = F / 9, m = F - 9 * t;
            o0[F] = s0v[t + 144 * m];
        }
        if (tid < 16) {
            const int F = 1280 + tid;
            const int t = F / 9, m = F - 9 * t;
            o0[F] = s0v[t + 144 * m];
        }
        float4* o1 = reinterpret_cast<float4*>(out1 + (size_t)b * OUT1_PER_B);
        if (tid < 144) o1[tid] = reinterpret_cast<const float4*>(sO1)[tid];
        // No third barrier: next-iter sT1d writes only happen after this thread passes
        // the compute-end barrier; sO* readers all passed the stage-end barrier.
    }
}

extern "C" void kernel_launch(void* const* d_in, const int* in_sizes, int n_in,
                              void* d_out, int out_size, void* d_ws, size_t ws_size,
                              hipStream_t stream) {
    const float* T1 = (const float*)d_in[0];
    const float* T2 = (const float*)d_in[1];
    float* out = (float*)d_out;

    const int B = in_sizes[0] / T1_PER_B;   // 20000

    float* out0 = out;
    float* out1 = out0 + (size_t)B * OUT0_PER_B;
    float* out2 = out1 + (size_t)B * OUT1_PER_B;

    int blocks = (B + 9) / 10;              // ~10 batches per block, uniform
    if (blocks > 2048) blocks = 2048;
    if (blocks < 1) blocks = 1;
    atc_kernel<<<dim3(blocks), dim3(256), 0, stream>>>(T1, T2, out0, out1, out2, B);
}

// Round 4
// 122.385 us; speedup vs baseline: 1.0259x; 1.0259x over previous
//
#include <hip/hip_runtime.h>

// B=20000, C=64, D=27
// out0[b,c,i,j] = sum_k T1[b,c,3i+k] * T2[b,9k+j] / sqrt(3)   (i,j in 0..8, k in 0..2)
// out1[b,c,i,j] = sum_k T1[b,c,9i+k] * T2[b,3k+j] / 3         (i,j in 0..2, k in 0..8)
// out2[b,c]     = dot(T1[b,c,:27], T2[b,:27]) / sqrt(27)

constexpr int D_DIM       = 27;
constexpr int T1_PER_B    = 1728;   // 432 float4
constexpr int OUT0_PER_B  = 5184;   // 1296 float4
constexpr int OUT1_PER_B  = 576;    // 144 float4
constexpr int OUT2_PER_B  = 64;
// sO0 slot stride: 144 == 0 (mod 8) made readback ds_read_b128 ~9-way bank-conflicted
// (9 lanes sharing t=F/9 hit the same 4-bank group). 145 is odd -> group = (t+m)%8,
// uniform across lanes. Bijective: slot = t + 145*m, t<144<=145.
constexpr int SLOT_STRIDE = 145;
constexpr int SO0_F4      = 144 + SLOT_STRIDE * 8;  // 1304 float4 = 20864 B

__global__ __launch_bounds__(256, 5) void atc_kernel(
    const float* __restrict__ T1, const float* __restrict__ T2,
    float* __restrict__ out0, float* __restrict__ out1, float* __restrict__ out2,
    int B)
{
    // sT1d[w][j] = T1[b, 3j+w]  (mod-3 de-interleave; makes all compute reads
    // lane-consecutive b128 or stride-3/9 scalar runs, all <=2 lanes/bank).
    __shared__ __align__(16) float sT1d[3][576];    //  6912 B
    __shared__ __align__(16) float sO0[4 * SO0_F4]; // 20864 B
    __shared__ __align__(16) float sO1[OUT1_PER_B]; //  2304 B
    // total 30080 B -> 5 blocks/CU (150.4 KB of 160), 20 waves/CU

    const int tid = threadIdx.x;
    const float n0 = 0.57735026918962576f;  // 1/sqrt(3)
    const float n1 = 0.33333333333333333f;  // 1/3
    const float n2 = 0.19245008972987526f;  // 1/sqrt(27)
    const int stride = gridDim.x;           // 1280: exactly 5 blocks/CU, single
                                            // block-wave, no residency tail

    int b = blockIdx.x;
    if (b >= B) return;

    // ---- prologue: prefetch T1[b] into registers ----
    float4 p0, p1;
    {
        const float4* t1v = reinterpret_cast<const float4*>(T1 + (size_t)b * T1_PER_B);
        p0 = t1v[tid];
        if (tid < 176) p1 = t1v[256 + tid];
    }

    while (true) {
        // ---- T2[b]: block-uniform -> scalar loads; latency covered by stage+barrier
        const float* t2p = T2 + (size_t)b * D_DIM;
        float s2[D_DIM];
        #pragma unroll
        for (int d = 0; d < D_DIM; ++d) s2[d] = t2p[d];

        // ---- stage: ds_write prefetched registers, mod-3 de-interleaved ----
        {
            const int g = tid, gd3 = g / 3, gm3 = g - gd3 * 3;
            #pragma unroll
            for (int u = 0; u < 4; ++u) {
                const int t  = gm3 + u;
                const int ge = (t >= 3) ? 1 : 0;
                sT1d[t - 3 * ge][g + gd3 + ge] = (&p0.x)[u];
            }
            if (tid < 176) {
                const int g2 = 256 + tid, gd3b = g2 / 3, gm3b = g2 - gd3b * 3;
                #pragma unroll
                for (int u = 0; u < 4; ++u) {
                    const int t  = gm3b + u;
                    const int ge = (t >= 3) ? 1 : 0;
                    sT1d[t - 3 * ge][g2 + gd3b + ge] = (&p1.x)[u];
                }
            }
        }
        __syncthreads();  // barrier A: sT1d ready

        const int bn = b + stride;
        // ---- prefetch next T1 tile NOW: latency hides under compute + readback ----
        if (bn < B) {
            const float4* t1n = reinterpret_cast<const float4*>(T1 + (size_t)bn * T1_PER_B);
            p0 = t1n[tid];
            if (tid < 176) p1 = t1n[256 + tid];
        }

        // ---- out0: threads 0-143, 4 whole rows each (9 aligned float4 out) ----
        if (tid < 144) {
            const float4 A0 = reinterpret_cast<const float4*>(&sT1d[0][0])[tid];
            const float4 A1 = reinterpret_cast<const float4*>(&sT1d[1][0])[tid];
            const float4 A2 = reinterpret_cast<const float4*>(&sT1d[2][0])[tid];
            const float a0[4] = {A0.x * n0, A0.y * n0, A0.z * n0, A0.w * n0};
            const float a1[4] = {A1.x * n0, A1.y * n0, A1.z * n0, A1.w * n0};
            const float a2[4] = {A2.x * n0, A2.y * n0, A2.z * n0, A2.w * n0};
            float4* so0 = reinterpret_cast<float4*>(sO0);
            #pragma unroll
            for (int m = 0; m < 9; ++m) {
                float4 r;
                #pragma unroll
                for (int u = 0; u < 4; ++u) {
                    const int e  = 4 * m + u;   // 0..35 compile-time
                    const int rr = e / 9;
                    const int j  = e - rr * 9;
                    (&r.x)[u] = a0[rr] * s2[j] + a1[rr] * s2[9 + j] + a2[rr] * s2[18 + j];
                }
                so0[tid + SLOT_STRIDE * m] = r;  // lane-consecutive: conflict-free
            }
        }

        // ---- out1 (threads 0-191) / out2 (wave 3, direct coalesced store) ----
        if (tid < 192) {
            const int R = tid;                   // R = 3c+i
            float av[3][3];
            #pragma unroll
            for (int w = 0; w < 3; ++w)
                #pragma unroll
                for (int p = 0; p < 3; ++p)
                    av[w][p] = sT1d[w][3 * R + p];  // = T1[9R+3p+w]
            #pragma unroll
            for (int j = 0; j < 3; ++j) {
                float v = 0.f;
                #pragma unroll
                for (int k = 0; k < 9; ++k)      // k = 3p+w
                    v += av[k % 3][k / 3] * s2[3 * k + j];
                sO1[3 * R + j] = v * n1;
            }
        } else {
            const int c = tid - 192;
            float v = 0.f;
            #pragma unroll
            for (int w = 0; w < 3; ++w)
                #pragma unroll
                for (int p = 0; p < 9; ++p)      // d = 3p+w
                    v += sT1d[w][9 * c + p] * s2[3 * p + w];
            out2[(size_t)b * OUT2_PER_B + c] = v * n2;
        }
        __syncthreads();  // barrier B: sO0/sO1 ready, sT1d free for next stage

        // ---- readback: coalesced float4 global stores ----
        float4* o0 = reinterpret_cast<float4*>(out0 + (size_t)b * OUT0_PER_B);
        const float4* s0v = reinterpret_cast<const float4*>(sO0);
        #pragma unroll
        for (int q = 0; q < 5; ++q) {
            const int F = q * 256 + tid;
            const int t = F / 9, m = F - 9 * t;
            o0[F] = s0v[t + SLOT_STRIDE * m];
        }
        if (tid < 16) {
            const int F = 1280 + tid;
            const int t = F / 9, m = F - 9 * t;
            o0[F] = s0v[t + SLOT_STRIDE * m];
        }
        float4* o1 = reinterpret_cast<float4*>(out1 + (size_t)b * OUT1_PER_B);
        if (tid < 144) o1[tid] = reinterpret_cast<const float4*>(sO1)[tid];

        if (bn >= B) break;
        b = bn;
        // No extra barrier: next stage's sT1d writes are ordered after barrier B,
        // and sO0/sO1 rewrites happen only after the next barrier A.
    }
}

extern "C" void kernel_launch(void* const* d_in, const int* in_sizes, int n_in,
                              void* d_out, int out_size, void* d_ws, size_t ws_size,
                              hipStream_t stream) {
    const float* T1 = (const float*)d_in[0];
    const float* T2 = (const float*)d_in[1];
    float* out = (float*)d_out;

    const int B = in_sizes[0] / T1_PER_B;   // 20000

    float* out0 = out;
    float* out1 = out0 + (size_t)B * OUT0_PER_B;
    float* out2 = out1 + (size_t)B * OUT1_PER_B;

    int blocks = 1280;                      // 5 blocks/CU x 256 CU, single wave
    if (blocks > B) blocks = B;
    atc_kernel<<<dim3(blocks), dim3(256), 0, stream>>>(T1, T2, out0, out1, out2, B);
}